// Round 1
// baseline (4240.310 us; speedup 1.0000x reference)
//
#include <hip/hip_runtime.h>
#include <math.h>

#define B_TOTAL 65536
#define D 512      // EMBED_DIM
#define H 8        // NUM_HEADS
#define K 128      // HID
#define M 64       // HEAD_DIM
#define G 512      // global hidden
#define D2 1024    // 2*EMBED_DIM
#define TILE 8
#define THREADS 256

__device__ __forceinline__ float gelu_exact(float x) {
    return 0.5f * x * (1.0f + erff(x * 0.70710678118654752440f));
}

// ---------------- Kernel A: per-head path -> per_aspect ----------------
// block: 256 threads, TILE=8 batch rows. LDS: xT(16K) xI(16K) h(32K) = 64KB.
// GEMM1: thread t owns head = t>>5, cols kk=(t&31)*4 .. +3, all 8 rows.
// GEMM2: thread t owns head = t>>5, cols m0=(t&31)*2 .. +1, all 8 rows.
__global__ __launch_bounds__(THREADS) void head_path_kernel(
    const float* __restrict__ text, const float* __restrict__ image,
    const float* __restrict__ W1, const float* __restrict__ b1,
    const float* __restrict__ ln1g, const float* __restrict__ ln1b,
    const float* __restrict__ W2, const float* __restrict__ b2,
    float* __restrict__ out_pa)
{
    __shared__ float sA[TILE * D];    // text rows, later oT [8][512]
    __shared__ float sB[TILE * D];    // image rows, later oI [8][512]
    __shared__ float sH[TILE * D2];   // h buffer [8][1024]

    const int tid = threadIdx.x;
    const int row0 = blockIdx.x * TILE;

    // ---- stage input rows (contiguous 4096-float chunks) ----
    {
        const float4* st = (const float4*)(text + (size_t)row0 * D);
        const float4* si = (const float4*)(image + (size_t)row0 * D);
        float4* dA = (float4*)sA;
        float4* dB = (float4*)sB;
        #pragma unroll
        for (int i = tid; i < TILE * D / 4; i += THREADS) { dA[i] = st[i]; dB[i] = si[i]; }
    }
    __syncthreads();

    const int head = tid >> 5;
    const int kk = (tid & 31) * 4;
    const float* w1p = W1 + (size_t)head * D * K + kk;

    for (int mod = 0; mod < 2; ++mod) {
        const float* xs = (mod == 0) ? sA : sB;
        float* os = (mod == 0) ? sA : sB;

        // ---- GEMM1: h = x @ W1[head] + b1 ----
        float acc[TILE][4];
        #pragma unroll
        for (int r = 0; r < TILE; ++r) { acc[r][0]=0.f; acc[r][1]=0.f; acc[r][2]=0.f; acc[r][3]=0.f; }

        for (int d0 = 0; d0 < D; d0 += 4) {
            float4 xv[TILE];
            #pragma unroll
            for (int r = 0; r < TILE; ++r) xv[r] = *(const float4*)(xs + r * D + d0);
            #pragma unroll
            for (int dd = 0; dd < 4; ++dd) {
                float4 wv = *(const float4*)(w1p + (size_t)(d0 + dd) * K);
                #pragma unroll
                for (int r = 0; r < TILE; ++r) {
                    float xr = (dd == 0) ? xv[r].x : (dd == 1) ? xv[r].y : (dd == 2) ? xv[r].z : xv[r].w;
                    acc[r][0] += xr * wv.x; acc[r][1] += xr * wv.y;
                    acc[r][2] += xr * wv.z; acc[r][3] += xr * wv.w;
                }
            }
        }
        {
            float4 bv = *(const float4*)(b1 + head * K + kk);
            #pragma unroll
            for (int r = 0; r < TILE; ++r) {
                float4 o;
                o.x = acc[r][0] + bv.x; o.y = acc[r][1] + bv.y;
                o.z = acc[r][2] + bv.z; o.w = acc[r][3] + bv.w;
                *(float4*)(sH + r * D2 + head * K + kk) = o;
            }
        }
        __syncthreads();

        // ---- LN + GELU per (row, head), 64 threads, rotated k to avoid bank conflicts ----
        if (tid < TILE * H) {
            const int r = tid >> 3, hd = tid & 7;
            float* hrow = sH + r * D2 + hd * K;
            const float* gp = ln1g + hd * K;
            const float* bp = ln1b + hd * K;
            const int rot = tid * 2 + (tid >> 4);
            float s = 0.f, s2 = 0.f;
            for (int j = 0; j < K; ++j) {
                int k2 = (j + rot) & (K - 1);
                float v = hrow[k2]; s += v; s2 += v * v;
            }
            float mu = s * (1.0f / K);
            float var = s2 * (1.0f / K) - mu * mu;
            float rs = rsqrtf(var + 1e-5f);
            for (int j = 0; j < K; ++j) {
                int k2 = (j + rot) & (K - 1);
                float v = (hrow[k2] - mu) * rs * gp[k2] + bp[k2];
                hrow[k2] = gelu_exact(v);
            }
        }
        __syncthreads();

        // ---- GEMM2: o = gelu(h) @ W2[head] + b2 -> overwrite x region ----
        const int m0 = (tid & 31) * 2;
        const float* w2p = W2 + (size_t)head * K * M + m0;
        float a2[TILE][2];
        #pragma unroll
        for (int r = 0; r < TILE; ++r) { a2[r][0] = 0.f; a2[r][1] = 0.f; }
        for (int k = 0; k < K; ++k) {
            float2 wv = *(const float2*)(w2p + (size_t)k * M);
            #pragma unroll
            for (int r = 0; r < TILE; ++r) {
                float hv = sH[r * D2 + head * K + k];
                a2[r][0] += hv * wv.x; a2[r][1] += hv * wv.y;
            }
        }
        {
            float2 b2v = *(const float2*)(b2 + head * M + m0);
            #pragma unroll
            for (int r = 0; r < TILE; ++r) {
                float2 o; o.x = a2[r][0] + b2v.x; o.y = a2[r][1] + b2v.y;
                *(float2*)(os + r * (H * M) + head * M + m0) = o;
            }
        }
        __syncthreads();
    }

    // ---- normalize + per-aspect cosine, 64 threads ----
    if (tid < TILE * H) {
        const int r = tid >> 3, hd = tid & 7;
        const float* ot = sA + r * 512 + hd * M;
        const float* oi = sB + r * 512 + hd * M;
        float nt = 0.f, ni = 0.f, dt = 0.f;
        for (int j = 0; j < M; ++j) {
            int m = (j + tid) & (M - 1);
            float a = ot[m], b = oi[m];
            nt += a * a; ni += b * b; dt += a * b;
        }
        float denom = fmaxf(sqrtf(nt), 1e-12f) * fmaxf(sqrtf(ni), 1e-12f);
        out_pa[(size_t)(row0 + r) * H + hd] = dt / denom;
    }
}

// ---------------- Kernel B: global path -> conflict ----------------
__global__ __launch_bounds__(THREADS) void global_path_kernel(
    const float* __restrict__ text, const float* __restrict__ image,
    const float* __restrict__ gW1, const float* __restrict__ gb1,
    const float* __restrict__ glng, const float* __restrict__ glnb,
    const float* __restrict__ gW2, const float* __restrict__ gb2,
    const float* __restrict__ aw, const float* __restrict__ pa,
    float* __restrict__ out_conflict)
{
    __shared__ float sX[TILE * D2];  // concat rows [8][1024]
    __shared__ float sG[TILE * G];   // pre-LN activations [8][512]

    const int tid = threadIdx.x;
    const int row0 = blockIdx.x * TILE;

    // ---- stage concat(text,image) rows ----
    for (int i = tid; i < TILE * D2 / 4; i += THREADS) {
        int f = i * 4;
        int r = f >> 10;
        int c = f & (D2 - 1);
        float4 v = (c < D) ? *(const float4*)(text + (size_t)(row0 + r) * D + c)
                           : *(const float4*)(image + (size_t)(row0 + r) * D + (c - D));
        *(float4*)(sX + f) = v;
    }
    __syncthreads();

    // ---- GEMM: s = gin @ gW1 + gb1 (512 cols; thread owns 2 cols x 8 rows) ----
    const int c0 = tid * 2;
    float acc[TILE][2];
    #pragma unroll
    for (int r = 0; r < TILE; ++r) { acc[r][0] = 0.f; acc[r][1] = 0.f; }
    for (int d0 = 0; d0 < D2; d0 += 4) {
        float4 xv[TILE];
        #pragma unroll
        for (int r = 0; r < TILE; ++r) xv[r] = *(const float4*)(sX + r * D2 + d0);
        #pragma unroll
        for (int dd = 0; dd < 4; ++dd) {
            float2 wv = *(const float2*)(gW1 + (size_t)(d0 + dd) * G + c0);
            #pragma unroll
            for (int r = 0; r < TILE; ++r) {
                float xr = (dd == 0) ? xv[r].x : (dd == 1) ? xv[r].y : (dd == 2) ? xv[r].z : xv[r].w;
                acc[r][0] += xr * wv.x; acc[r][1] += xr * wv.y;
            }
        }
    }
    {
        float2 gbv = *(const float2*)(gb1 + c0);
        #pragma unroll
        for (int r = 0; r < TILE; ++r) {
            float2 o; o.x = acc[r][0] + gbv.x; o.y = acc[r][1] + gbv.y;
            *(float2*)(sG + r * G + c0) = o;
        }
    }
    __syncthreads();

    // ---- LN + GELU + dot(gW2): 8 groups of 32 lanes, one row each ----
    const int grp = tid >> 5, lane = tid & 31;
    const int r = grp;
    float s = 0.f, s2 = 0.f;
    for (int c = lane; c < G; c += 32) { float v = sG[r * G + c]; s += v; s2 += v * v; }
    #pragma unroll
    for (int off = 16; off >= 1; off >>= 1) {
        s += __shfl_xor(s, off, 64);
        s2 += __shfl_xor(s2, off, 64);
    }
    float mu = s * (1.0f / G);
    float var = s2 * (1.0f / G) - mu * mu;
    float rs = rsqrtf(var + 1e-5f);
    float dp = 0.f;
    for (int c = lane; c < G; c += 32) {
        float v = (sG[r * G + c] - mu) * rs * glng[c] + glnb[c];
        dp += gelu_exact(v) * gW2[c];
    }
    #pragma unroll
    for (int off = 16; off >= 1; off >>= 1) dp += __shfl_xor(dp, off, 64);

    if (lane == 0) {
        float z = dp + gb2[0];
        float gs = 1.0f / (1.0f + expf(-z));
        float w[8]; float mx = -1e30f;
        #pragma unroll
        for (int h2 = 0; h2 < 8; ++h2) { w[h2] = aw[h2]; mx = fmaxf(mx, w[h2]); }
        float sum = 0.f;
        #pragma unroll
        for (int h2 = 0; h2 < 8; ++h2) { w[h2] = expf(w[h2] - mx); sum += w[h2]; }
        float ws = 0.f;
        const float* par = pa + (size_t)(row0 + r) * H;
        #pragma unroll
        for (int h2 = 0; h2 < 8; ++h2) ws += par[h2] * (w[h2] / sum);
        float conf = 1.0f - (0.7f * ws + 0.3f * gs);
        conf = fminf(fmaxf(conf, 0.0f), 1.0f);
        out_conflict[row0 + r] = conf;
    }
}

extern "C" void kernel_launch(void* const* d_in, const int* in_sizes, int n_in,
                              void* d_out, int out_size, void* d_ws, size_t ws_size,
                              hipStream_t stream) {
    const float* text  = (const float*)d_in[0];
    const float* image = (const float*)d_in[1];
    const float* W1    = (const float*)d_in[2];
    const float* b1    = (const float*)d_in[3];
    const float* ln1g  = (const float*)d_in[4];
    const float* ln1b  = (const float*)d_in[5];
    const float* W2    = (const float*)d_in[6];
    const float* b2    = (const float*)d_in[7];
    const float* aw    = (const float*)d_in[8];
    const float* gW1   = (const float*)d_in[9];
    const float* gb1   = (const float*)d_in[10];
    const float* glng  = (const float*)d_in[11];
    const float* glnb  = (const float*)d_in[12];
    const float* gW2   = (const float*)d_in[13];
    const float* gb2   = (const float*)d_in[14];

    float* out = (float*)d_out;
    float* out_pa = out + B_TOTAL;   // per_aspect region [65536][8]

    dim3 grid(B_TOTAL / TILE), block(THREADS);
    head_path_kernel<<<grid, block, 0, stream>>>(text, image, W1, b1, ln1g, ln1b, W2, b2, out_pa);
    global_path_kernel<<<grid, block, 0, stream>>>(text, image, gW1, gb1, glng, glnb, gW2, gb2, aw, out_pa, out);
}

// Round 2
// 1522.275 us; speedup vs baseline: 2.7855x; 2.7855x over previous
//
#include <hip/hip_runtime.h>
#include <math.h>

#define B_TOTAL 65536
#define D 512
#define H 8
#define K 128
#define M 64
#define D2 1024

typedef __attribute__((ext_vector_type(8))) short short8v;   // 8 bf16 (4 VGPRs)
typedef __attribute__((ext_vector_type(4))) float f32x4;

__device__ __forceinline__ unsigned short f2bf(float f) {
    union { float f; unsigned u; } v; v.f = f;
    unsigned r = v.u + 0x7FFF + ((v.u >> 16) & 1);   // RNE
    return (unsigned short)(r >> 16);
}

__device__ __forceinline__ float gelu_exact(float x) {
    return 0.5f * x * (1.0f + erff(x * 0.70710678118654752440f));
}

// ============== converter: weights -> fragment-linear bf16 in ws ==============
// W1T: [hd(8)][kblk(16)][nt(8)][lane(64)][j(8)]  elem j = W1[hd][32kb+8(l>>4)+j][16nt+(l&15)]
// W2T: [hd(8)][kblk(4)][nt(4)][lane][j]          elem j = W2[hd][32kb+8(l>>4)+j][16nt+(l&15)]
// gW1T:[kblk(32)][nt(32)][lane][j]               elem j = gW1[32kb+8(l>>4)+j][16nt+(l&15)]
__global__ void convert_weights(const float* __restrict__ W1, const float* __restrict__ W2,
                                const float* __restrict__ gW1,
                                unsigned short* __restrict__ W1T, unsigned short* __restrict__ W2T,
                                unsigned short* __restrict__ gW1T)
{
    int t = blockIdx.x * 256 + threadIdx.x;
    if (t < 65536) {
        int l = t & 63, nt = (t >> 6) & 7, kb = (t >> 9) & 15, hd = t >> 13;
        int n = 16 * nt + (l & 15);
        int k = 32 * kb + 8 * (l >> 4);
        const float* s = W1 + (size_t)hd * 65536 + (size_t)k * 128 + n;
        short8v o;
        #pragma unroll
        for (int j = 0; j < 8; ++j) o[j] = (short)f2bf(s[(size_t)j * 128]);
        *(short8v*)(W1T + (size_t)t * 8) = o;
    } else if (t < 65536 + 8192) {
        int u = t - 65536;
        int l = u & 63, nt = (u >> 6) & 3, kb = (u >> 8) & 3, hd = u >> 10;
        int m = 16 * nt + (l & 15);
        int k = 32 * kb + 8 * (l >> 4);
        const float* s = W2 + (size_t)hd * 8192 + (size_t)k * 64 + m;
        short8v o;
        #pragma unroll
        for (int j = 0; j < 8; ++j) o[j] = (short)f2bf(s[(size_t)j * 64]);
        *(short8v*)(W2T + (size_t)u * 8) = o;
    } else if (t < 65536 + 8192 + 65536) {
        int u = t - 73728;
        int l = u & 63, nt = (u >> 6) & 31, kb = u >> 11;
        int n = 16 * nt + (l & 15);
        int k = 32 * kb + 8 * (l >> 4);
        const float* s = gW1 + (size_t)k * 512 + n;
        short8v o;
        #pragma unroll
        for (int j = 0; j < 8; ++j) o[j] = (short)f2bf(s[(size_t)j * 512]);
        *(short8v*)(gW1T + (size_t)u * 8) = o;
    }
}

// ============== kernel A: per-head path -> per_aspect ==============
// 32 batch rows/block; A-tile 64 rows (interleaved: A-row r -> batch row0+8*(r>>4)+(r&7),
// image iff r&8). Wave w computes heads 2w, 2w+1 over all 64 rows.
__global__ __launch_bounds__(256, 2) void head_path(
    const float* __restrict__ text, const float* __restrict__ image,
    const unsigned short* __restrict__ W1T, const float* __restrict__ b1,
    const float* __restrict__ ln1g, const float* __restrict__ ln1b,
    const unsigned short* __restrict__ W2T, const float* __restrict__ b2,
    float* __restrict__ out_pa)
{
    __shared__ unsigned short sX[64 * 512];     // 64KB, XOR-swizzled bf16 A-tile
    __shared__ unsigned short hB[4][640];       // per-wave [16][40] h chunk (1280B each)

    const int tid = threadIdx.x;
    const int w = tid >> 6;
    const int lane = tid & 63;
    const int lg = lane >> 4;     // frag k-group AND C-layout row group g
    const int lc = lane & 15;     // frag m/n index AND C-layout col
    const size_t row0 = (size_t)blockIdx.x * 32;

    // ---- stage A-tile: f32 -> bf16, swizzled ----
    #pragma unroll
    for (int i = 0; i < 32; ++i) {
        int idx = tid + 256 * i;           // 0..8191 float4 units
        int r = idx >> 7;
        int c4 = idx & 127;
        size_t b = row0 + 8 * (r >> 4) + (r & 7);
        const float* src = ((r >> 3) & 1) ? image : text;
        float4 v = *(const float4*)(src + b * 512 + 4 * c4);
        uint2 pk;
        pk.x = (unsigned)f2bf(v.x) | ((unsigned)f2bf(v.y) << 16);
        pk.y = (unsigned)f2bf(v.z) | ((unsigned)f2bf(v.w) << 16);
        int byteoff = r * 1024 + ((8 * c4) ^ ((r & 7) << 4));
        *(uint2*)((char*)sX + byteoff) = pk;
    }
    __syncthreads();

    const char* W1b = (const char*)W1T;
    const char* W2b = (const char*)W2T;
    unsigned short* hb = &hB[w][0];

    for (int hh = 0; hh < 2; ++hh) {
        const int hd = 2 * w + hh;

        // ---- GEMM1: h[64][128] for this head ----
        f32x4 acc[4][8];
        #pragma unroll
        for (int rt = 0; rt < 4; ++rt)
            #pragma unroll
            for (int nt = 0; nt < 8; ++nt) acc[rt][nt] = (f32x4){0.f, 0.f, 0.f, 0.f};

        for (int k0 = 0; k0 < 16; ++k0) {
            short8v af[4];
            #pragma unroll
            for (int rt = 0; rt < 4; ++rt) {
                int r = 16 * rt + lc;
                int kbyte = (64 * k0 + 16 * lg) ^ ((r & 7) << 4);
                af[rt] = *(const short8v*)((const char*)sX + r * 1024 + kbyte);
            }
            const char* bb = W1b + hd * 131072 + k0 * 8192 + lane * 16;
            #pragma unroll
            for (int nt = 0; nt < 8; ++nt) {
                short8v bf_ = *(const short8v*)(bb + nt * 1024);
                #pragma unroll
                for (int rt = 0; rt < 4; ++rt)
                    acc[rt][nt] = __builtin_amdgcn_mfma_f32_16x16x32_bf16(af[rt], bf_, acc[rt][nt], 0, 0, 0);
            }
        }

        // ---- + b1, LN stats (reduce over 8 nt in-lane, 16 lanes via shfl_xor) ----
        #pragma unroll
        for (int nt = 0; nt < 8; ++nt) {
            float bv = b1[hd * 128 + 16 * nt + lc];
            #pragma unroll
            for (int rt = 0; rt < 4; ++rt)
                #pragma unroll
                for (int reg = 0; reg < 4; ++reg) acc[rt][nt][reg] += bv;
        }
        float mu[4][4], rsig[4][4];
        #pragma unroll
        for (int rt = 0; rt < 4; ++rt)
            #pragma unroll
            for (int reg = 0; reg < 4; ++reg) {
                float s = 0.f, s2 = 0.f;
                #pragma unroll
                for (int nt = 0; nt < 8; ++nt) { float v = acc[rt][nt][reg]; s += v; s2 += v * v; }
                #pragma unroll
                for (int off = 1; off < 16; off <<= 1) {
                    s += __shfl_xor(s, off, 64);
                    s2 += __shfl_xor(s2, off, 64);
                }
                float m = s * (1.0f / 128.0f);
                float var = s2 * (1.0f / 128.0f) - m * m;
                mu[rt][reg] = m;
                rsig[rt][reg] = rsqrtf(var + 1e-5f);
            }

        // ---- LN apply + GELU (in-register) ----
        #pragma unroll
        for (int nt = 0; nt < 8; ++nt) {
            float gv = ln1g[hd * 128 + 16 * nt + lc];
            float bv = ln1b[hd * 128 + 16 * nt + lc];
            #pragma unroll
            for (int rt = 0; rt < 4; ++rt)
                #pragma unroll
                for (int reg = 0; reg < 4; ++reg) {
                    float v = (acc[rt][nt][reg] - mu[rt][reg]) * rsig[rt][reg] * gv + bv;
                    acc[rt][nt][reg] = gelu_exact(v);
                }
        }

        // ---- GEMM2 via per-(kb,rt) LDS transpose chunks [16][40] (wave-private) ----
        f32x4 acc2[4][4];
        #pragma unroll
        for (int rt = 0; rt < 4; ++rt)
            #pragma unroll
            for (int nt2 = 0; nt2 < 4; ++nt2) acc2[rt][nt2] = (f32x4){0.f, 0.f, 0.f, 0.f};

        for (int kb = 0; kb < 4; ++kb) {
            short8v bf2[4];
            #pragma unroll
            for (int nt2 = 0; nt2 < 4; ++nt2)
                bf2[nt2] = *(const short8v*)(W2b + hd * 16384 + kb * 4096 + nt2 * 1024 + lane * 16);
            #pragma unroll
            for (int rt = 0; rt < 4; ++rt) {
                #pragma unroll
                for (int ntl = 0; ntl < 2; ++ntl) {
                    int nt = 2 * kb + ntl;
                    int kk = 16 * ntl + lc;
                    #pragma unroll
                    for (int reg = 0; reg < 4; ++reg)
                        hb[(4 * lg + reg) * 40 + kk] = f2bf(acc[rt][nt][reg]);
                }
                short8v af2 = *(const short8v*)((const char*)hb + lc * 80 + 16 * lg);
                #pragma unroll
                for (int nt2 = 0; nt2 < 4; ++nt2)
                    acc2[rt][nt2] = __builtin_amdgcn_mfma_f32_16x16x32_bf16(af2, bf2[nt2], acc2[rt][nt2], 0, 0, 0);
            }
        }

        // ---- + b2, norms, text<->image cosine via shfl_xor 32 ----
        #pragma unroll
        for (int nt2 = 0; nt2 < 4; ++nt2) {
            float bv = b2[hd * 64 + 16 * nt2 + lc];
            #pragma unroll
            for (int rt = 0; rt < 4; ++rt)
                #pragma unroll
                for (int reg = 0; reg < 4; ++reg) acc2[rt][nt2][reg] += bv;
        }
        #pragma unroll
        for (int rt = 0; rt < 4; ++rt)
            #pragma unroll
            for (int reg = 0; reg < 4; ++reg) {
                float nrm = 0.f, prod = 0.f;
                #pragma unroll
                for (int nt2 = 0; nt2 < 4; ++nt2) {
                    float o = acc2[rt][nt2][reg];
                    float oo = __shfl_xor(o, 32, 64);
                    nrm += o * o;
                    prod += o * oo;
                }
                #pragma unroll
                for (int off = 1; off < 16; off <<= 1) {
                    nrm += __shfl_xor(nrm, off, 64);
                    prod += __shfl_xor(prod, off, 64);
                }
                float nother = __shfl_xor(nrm, 32, 64);
                if (lg < 2 && lc == 0) {
                    size_t b = row0 + 8 * rt + 4 * lg + reg;
                    float denom = fmaxf(sqrtf(nrm), 1e-12f) * fmaxf(sqrtf(nother), 1e-12f);
                    out_pa[b * 8 + hd] = prod / denom;
                }
            }
    }
}

// ============== kernel B: global path -> conflict ==============
// 64 rows/block; wave w owns cols 128w..128w+127; K=1024 staged in 4 chunks of 256.
__global__ __launch_bounds__(256, 2) void global_path(
    const float* __restrict__ text, const float* __restrict__ image,
    const unsigned short* __restrict__ gW1T, const float* __restrict__ gb1,
    const float* __restrict__ glng, const float* __restrict__ glnb,
    const float* __restrict__ gW2, const float* __restrict__ gb2,
    const float* __restrict__ aw, const float* __restrict__ pa,
    float* __restrict__ out_conflict)
{
    __shared__ unsigned short sG[64 * 256];    // 32KB swizzled gin chunk
    __shared__ float sStat[4][64][2];
    __shared__ float sDot[4][64];

    const int tid = threadIdx.x;
    const int w = tid >> 6;
    const int lane = tid & 63;
    const int lg = lane >> 4;
    const int lc = lane & 15;
    const size_t row0 = (size_t)blockIdx.x * 64;

    f32x4 acc[4][8];
    #pragma unroll
    for (int rt = 0; rt < 4; ++rt)
        #pragma unroll
        for (int nt = 0; nt < 8; ++nt) acc[rt][nt] = (f32x4){0.f, 0.f, 0.f, 0.f};

    const char* gWb = (const char*)gW1T;

    for (int kc = 0; kc < 4; ++kc) {
        __syncthreads();
        #pragma unroll
        for (int i = 0; i < 16; ++i) {
            int idx = tid + 256 * i;       // 0..4095 float4 units
            int r = idx >> 6;
            int c4 = idx & 63;
            int gk = 256 * kc + 4 * c4;
            const float* src = (gk < 512) ? (text + (row0 + r) * 512 + gk)
                                          : (image + (row0 + r) * 512 + (gk - 512));
            float4 v = *(const float4*)src;
            uint2 pk;
            pk.x = (unsigned)f2bf(v.x) | ((unsigned)f2bf(v.y) << 16);
            pk.y = (unsigned)f2bf(v.z) | ((unsigned)f2bf(v.w) << 16);
            int byteoff = r * 512 + ((8 * c4) ^ ((r & 7) << 4));
            *(uint2*)((char*)sG + byteoff) = pk;
        }
        __syncthreads();

        for (int k0 = 0; k0 < 8; ++k0) {
            short8v af[4];
            #pragma unroll
            for (int rt = 0; rt < 4; ++rt) {
                int r = 16 * rt + lc;
                int kbyte = (64 * k0 + 16 * lg) ^ ((r & 7) << 4);
                af[rt] = *(const short8v*)((const char*)sG + r * 512 + kbyte);
            }
            int kblk = 8 * kc + k0;
            const char* bb = gWb + kblk * 32768 + (8 * w) * 1024 + lane * 16;
            #pragma unroll
            for (int nt = 0; nt < 8; ++nt) {
                short8v bf_ = *(const short8v*)(bb + nt * 1024);
                #pragma unroll
                for (int rt = 0; rt < 4; ++rt)
                    acc[rt][nt] = __builtin_amdgcn_mfma_f32_16x16x32_bf16(af[rt], bf_, acc[rt][nt], 0, 0, 0);
            }
        }
    }

    // ---- + gb1, LN partials to LDS ----
    #pragma unroll
    for (int nt = 0; nt < 8; ++nt) {
        float bv = gb1[(8 * w + nt) * 16 + lc];
        #pragma unroll
        for (int rt = 0; rt < 4; ++rt)
            #pragma unroll
            for (int reg = 0; reg < 4; ++reg) acc[rt][nt][reg] += bv;
    }
    #pragma unroll
    for (int rt = 0; rt < 4; ++rt)
        #pragma unroll
        for (int reg = 0; reg < 4; ++reg) {
            float s = 0.f, s2 = 0.f;
            #pragma unroll
            for (int nt = 0; nt < 8; ++nt) { float v = acc[rt][nt][reg]; s += v; s2 += v * v; }
            #pragma unroll
            for (int off = 1; off < 16; off <<= 1) {
                s += __shfl_xor(s, off, 64);
                s2 += __shfl_xor(s2, off, 64);
            }
            if (lc == 0) {
                int r = 16 * rt + 4 * lg + reg;
                sStat[w][r][0] = s;
                sStat[w][r][1] = s2;
            }
        }
    __syncthreads();

    float mu[4][4], rsg[4][4];
    #pragma unroll
    for (int rt = 0; rt < 4; ++rt)
        #pragma unroll
        for (int reg = 0; reg < 4; ++reg) {
            int r = 16 * rt + 4 * lg + reg;
            float s = sStat[0][r][0] + sStat[1][r][0] + sStat[2][r][0] + sStat[3][r][0];
            float s2 = sStat[0][r][1] + sStat[1][r][1] + sStat[2][r][1] + sStat[3][r][1];
            float m = s * (1.0f / 512.0f);
            float var = s2 * (1.0f / 512.0f) - m * m;
            mu[rt][reg] = m;
            rsg[rt][reg] = rsqrtf(var + 1e-5f);
        }

    // ---- LN + GELU + dot(gW2) partials ----
    float dp[4][4];
    #pragma unroll
    for (int rt = 0; rt < 4; ++rt)
        #pragma unroll
        for (int reg = 0; reg < 4; ++reg) dp[rt][reg] = 0.f;
    #pragma unroll
    for (int nt = 0; nt < 8; ++nt) {
        int col = (8 * w + nt) * 16 + lc;
        float gv = glng[col], bv = glnb[col], wv = gW2[col];
        #pragma unroll
        for (int rt = 0; rt < 4; ++rt)
            #pragma unroll
            for (int reg = 0; reg < 4; ++reg) {
                float v = (acc[rt][nt][reg] - mu[rt][reg]) * rsg[rt][reg] * gv + bv;
                dp[rt][reg] += gelu_exact(v) * wv;
            }
    }
    #pragma unroll
    for (int rt = 0; rt < 4; ++rt)
        #pragma unroll
        for (int reg = 0; reg < 4; ++reg) {
            float d = dp[rt][reg];
            #pragma unroll
            for (int off = 1; off < 16; off <<= 1) d += __shfl_xor(d, off, 64);
            if (lc == 0) sDot[w][16 * rt + 4 * lg + reg] = d;
        }
    __syncthreads();

    if (tid < 64) {
        int r = tid;
        float z = sDot[0][r] + sDot[1][r] + sDot[2][r] + sDot[3][r] + gb2[0];
        float gs = 1.0f / (1.0f + expf(-z));
        float wv[8], mx = -1e30f;
        #pragma unroll
        for (int i = 0; i < 8; ++i) { wv[i] = aw[i]; mx = fmaxf(mx, wv[i]); }
        float sum = 0.f;
        #pragma unroll
        for (int i = 0; i < 8; ++i) { wv[i] = expf(wv[i] - mx); sum += wv[i]; }
        float inv = 1.0f / sum;
        const float* par = pa + (row0 + r) * 8;
        float wsim = 0.f;
        #pragma unroll
        for (int i = 0; i < 8; ++i) wsim += par[i] * wv[i] * inv;
        float conf = 1.0f - (0.7f * wsim + 0.3f * gs);
        out_conflict[row0 + r] = fminf(fmaxf(conf, 0.0f), 1.0f);
    }
}

extern "C" void kernel_launch(void* const* d_in, const int* in_sizes, int n_in,
                              void* d_out, int out_size, void* d_ws, size_t ws_size,
                              hipStream_t stream) {
    const float* text  = (const float*)d_in[0];
    const float* image = (const float*)d_in[1];
    const float* W1    = (const float*)d_in[2];
    const float* b1    = (const float*)d_in[3];
    const float* ln1g  = (const float*)d_in[4];
    const float* ln1b  = (const float*)d_in[5];
    const float* W2    = (const float*)d_in[6];
    const float* b2    = (const float*)d_in[7];
    const float* aw    = (const float*)d_in[8];
    const float* gW1   = (const float*)d_in[9];
    const float* gb1   = (const float*)d_in[10];
    const float* glng  = (const float*)d_in[11];
    const float* glnb  = (const float*)d_in[12];
    const float* gW2   = (const float*)d_in[13];
    const float* gb2   = (const float*)d_in[14];

    unsigned short* W1T  = (unsigned short*)d_ws;                          // 1MB
    unsigned short* W2T  = (unsigned short*)((char*)d_ws + 1048576);       // 128KB
    unsigned short* gW1T = (unsigned short*)((char*)d_ws + 1179648);       // 1MB

    float* out = (float*)d_out;
    float* out_pa = out + B_TOTAL;

    convert_weights<<<544, 256, 0, stream>>>(W1, W2, gW1, W1T, W2T, gW1T);
    head_path<<<2048, 256, 0, stream>>>(text, image, W1T, b1, ln1g, ln1b, W2T, b2, out_pa);
    global_path<<<1024, 256, 0, stream>>>(text, image, gW1T, gb1, glng, glnb, gW2, gb2, aw, out_pa, out);
}

// Round 3
// 1266.454 us; speedup vs baseline: 3.3482x; 1.2020x over previous
//
#include <hip/hip_runtime.h>
#include <math.h>

#define B_TOTAL 65536
#define D 512
#define H 8
#define K 128
#define M 64
#define D2 1024

typedef __attribute__((ext_vector_type(8))) short short8v;   // 8 bf16 (4 VGPRs)
typedef __attribute__((ext_vector_type(4))) float f32x4;

__device__ __forceinline__ unsigned short f2bf(float f) {
    union { float f; unsigned u; } v; v.f = f;
    unsigned r = v.u + 0x7FFF + ((v.u >> 16) & 1);   // RNE
    return (unsigned short)(r >> 16);
}

__device__ __forceinline__ float gelu_exact(float x) {
    return 0.5f * x * (1.0f + erff(x * 0.70710678118654752440f));
}

// ============== converter: weights -> fragment-linear bf16 in ws ==============
// W1T: [hd(8)][kblk(16)][nt(8)][lane(64)][j(8)]  elem j = W1[hd][32kb+8(l>>4)+j][16nt+(l&15)]
// W2T: [hd(8)][kblk(4)][nt(4)][lane][j]          elem j = W2[hd][32kb+8(l>>4)+j][16nt+(l&15)]
// gW1T:[kblk(32)][nt(32)][lane][j]               elem j = gW1[32kb+8(l>>4)+j][16nt+(l&15)]
__global__ void convert_weights(const float* __restrict__ W1, const float* __restrict__ W2,
                                const float* __restrict__ gW1,
                                unsigned short* __restrict__ W1T, unsigned short* __restrict__ W2T,
                                unsigned short* __restrict__ gW1T)
{
    int t = blockIdx.x * 256 + threadIdx.x;
    if (t < 65536) {
        int l = t & 63, nt = (t >> 6) & 7, kb = (t >> 9) & 15, hd = t >> 13;
        int n = 16 * nt + (l & 15);
        int k = 32 * kb + 8 * (l >> 4);
        const float* s = W1 + (size_t)hd * 65536 + (size_t)k * 128 + n;
        short8v o;
        #pragma unroll
        for (int j = 0; j < 8; ++j) o[j] = (short)f2bf(s[(size_t)j * 128]);
        *(short8v*)(W1T + (size_t)t * 8) = o;
    } else if (t < 65536 + 8192) {
        int u = t - 65536;
        int l = u & 63, nt = (u >> 6) & 3, kb = (u >> 8) & 3, hd = u >> 10;
        int m = 16 * nt + (l & 15);
        int k = 32 * kb + 8 * (l >> 4);
        const float* s = W2 + (size_t)hd * 8192 + (size_t)k * 64 + m;
        short8v o;
        #pragma unroll
        for (int j = 0; j < 8; ++j) o[j] = (short)f2bf(s[(size_t)j * 64]);
        *(short8v*)(W2T + (size_t)u * 8) = o;
    } else if (t < 65536 + 8192 + 65536) {
        int u = t - 73728;
        int l = u & 63, nt = (u >> 6) & 31, kb = u >> 11;
        int n = 16 * nt + (l & 15);
        int k = 32 * kb + 8 * (l >> 4);
        const float* s = gW1 + (size_t)k * 512 + n;
        short8v o;
        #pragma unroll
        for (int j = 0; j < 8; ++j) o[j] = (short)f2bf(s[(size_t)j * 512]);
        *(short8v*)(gW1T + (size_t)u * 8) = o;
    }
}

// ============== fused kernel: head path + global path ==============
// 32 batch rows/block, 4 waves. A-tile = 64 A-rows (0..31 text, 32..63 image) x 512k,
// bf16 swizzled, LDS-resident. Wave w: heads 2w, 2w+1 (sequential), then global
// col-slice [128w, 128w+128). B-fragments prefetched 1 k0 deep from L2.
__global__ __launch_bounds__(256, 2) void fused_path(
    const float* __restrict__ text, const float* __restrict__ image,
    const unsigned short* __restrict__ W1T, const float* __restrict__ b1,
    const float* __restrict__ ln1g, const float* __restrict__ ln1b,
    const unsigned short* __restrict__ W2T, const float* __restrict__ b2,
    const unsigned short* __restrict__ gW1T, const float* __restrict__ gb1,
    const float* __restrict__ glng, const float* __restrict__ glnb,
    const float* __restrict__ gW2, const float* __restrict__ gb2,
    const float* __restrict__ aw,
    float* __restrict__ out_conflict, float* __restrict__ out_pa)
{
    __shared__ unsigned short sX[64 * 512];     // 64KB swizzled bf16 A-tile
    __shared__ unsigned short hB[4][640];       // per-wave [16][40] transpose chunk
    __shared__ float sStat[4][32][2];
    __shared__ float sDot[4][32];
    __shared__ float sPa[32][8];

    const int tid = threadIdx.x;
    const int w = tid >> 6;
    const int lane = tid & 63;
    const int lg = lane >> 4;
    const int lc = lane & 15;
    const int xm = (lc & 7) << 4;               // per-lane XOR swizzle mask (rows 16rt+lc)
    const size_t row0 = (size_t)blockIdx.x * 32;

    // ---- stage A-tile once: rows 0..31 text, 32..63 image ----
    #pragma unroll
    for (int i = 0; i < 32; ++i) {
        int idx = tid + 256 * i;                // 0..8191 float4 units
        int r = idx >> 7;
        int c4 = idx & 127;
        const float* src = (r < 32) ? (text + (row0 + r) * 512 + 4 * c4)
                                    : (image + (row0 + (r - 32)) * 512 + 4 * c4);
        float4 v = *(const float4*)src;
        uint2 pk;
        pk.x = (unsigned)f2bf(v.x) | ((unsigned)f2bf(v.y) << 16);
        pk.y = (unsigned)f2bf(v.z) | ((unsigned)f2bf(v.w) << 16);
        int byteoff = r * 1024 + ((8 * c4) ^ ((r & 7) << 4));
        *(uint2*)((char*)sX + byteoff) = pk;
    }
    __syncthreads();

    const char* sXb = (const char*)sX;
    const char* W1b = (const char*)W1T;
    const char* W2b = (const char*)W2T;
    const char* gWb = (const char*)gW1T;
    unsigned short* hb = &hB[w][0];

    // ================= head tasks =================
    for (int hh = 0; hh < 2; ++hh) {
        const int hd = 2 * w + hh;

        // ---- GEMM1: h[64][128], B prefetched 1-deep ----
        f32x4 acc[4][8];
        #pragma unroll
        for (int rt = 0; rt < 4; ++rt)
            #pragma unroll
            for (int nt = 0; nt < 8; ++nt) acc[rt][nt] = (f32x4){0.f, 0.f, 0.f, 0.f};

        const char* bb = W1b + hd * 131072 + lane * 16;
        short8v bfA[8], bfB[8];
        #pragma unroll
        for (int nt = 0; nt < 8; ++nt) bfA[nt] = *(const short8v*)(bb + nt * 1024);

        #pragma unroll
        for (int k0 = 0; k0 < 16; ++k0) {
            short8v* cur = (k0 & 1) ? bfB : bfA;
            short8v* nxt = (k0 & 1) ? bfA : bfB;
            if (k0 + 1 < 16) {
                #pragma unroll
                for (int nt = 0; nt < 8; ++nt)
                    nxt[nt] = *(const short8v*)(bb + (k0 + 1) * 8192 + nt * 1024);
            }
            short8v af[4];
            #pragma unroll
            for (int rt = 0; rt < 4; ++rt)
                af[rt] = *(const short8v*)(sXb + (16 * rt + lc) * 1024 + ((64 * k0 + 16 * lg) ^ xm));
            #pragma unroll
            for (int nt = 0; nt < 8; ++nt)
                #pragma unroll
                for (int rt = 0; rt < 4; ++rt)
                    acc[rt][nt] = __builtin_amdgcn_mfma_f32_16x16x32_bf16(af[rt], cur[nt], acc[rt][nt], 0, 0, 0);
        }

        // ---- + b1, LN stats ----
        #pragma unroll
        for (int nt = 0; nt < 8; ++nt) {
            float bv = b1[hd * 128 + 16 * nt + lc];
            #pragma unroll
            for (int rt = 0; rt < 4; ++rt)
                #pragma unroll
                for (int reg = 0; reg < 4; ++reg) acc[rt][nt][reg] += bv;
        }
        float mu[4][4], rsig[4][4];
        #pragma unroll
        for (int rt = 0; rt < 4; ++rt)
            #pragma unroll
            for (int reg = 0; reg < 4; ++reg) {
                float s = 0.f, s2 = 0.f;
                #pragma unroll
                for (int nt = 0; nt < 8; ++nt) { float v = acc[rt][nt][reg]; s += v; s2 += v * v; }
                #pragma unroll
                for (int off = 1; off < 16; off <<= 1) {
                    s += __shfl_xor(s, off, 64);
                    s2 += __shfl_xor(s2, off, 64);
                }
                float m = s * (1.0f / 128.0f);
                float var = s2 * (1.0f / 128.0f) - m * m;
                mu[rt][reg] = m;
                rsig[rt][reg] = rsqrtf(var + 1e-5f);
            }

        // ---- LN apply + GELU ----
        #pragma unroll
        for (int nt = 0; nt < 8; ++nt) {
            float gv = ln1g[hd * 128 + 16 * nt + lc];
            float bv = ln1b[hd * 128 + 16 * nt + lc];
            #pragma unroll
            for (int rt = 0; rt < 4; ++rt)
                #pragma unroll
                for (int reg = 0; reg < 4; ++reg) {
                    float v = (acc[rt][nt][reg] - mu[rt][reg]) * rsig[rt][reg] * gv + bv;
                    acc[rt][nt][reg] = gelu_exact(v);
                }
        }

        // ---- GEMM2 via wave-private LDS transpose chunks ----
        f32x4 acc2[4][4];
        #pragma unroll
        for (int rt = 0; rt < 4; ++rt)
            #pragma unroll
            for (int nt2 = 0; nt2 < 4; ++nt2) acc2[rt][nt2] = (f32x4){0.f, 0.f, 0.f, 0.f};

        #pragma unroll
        for (int kb = 0; kb < 4; ++kb) {
            short8v bf2[4];
            #pragma unroll
            for (int nt2 = 0; nt2 < 4; ++nt2)
                bf2[nt2] = *(const short8v*)(W2b + hd * 16384 + kb * 4096 + nt2 * 1024 + lane * 16);
            #pragma unroll
            for (int rt = 0; rt < 4; ++rt) {
                #pragma unroll
                for (int ntl = 0; ntl < 2; ++ntl) {
                    int nt = 2 * kb + ntl;
                    int kk = 16 * ntl + lc;
                    #pragma unroll
                    for (int reg = 0; reg < 4; ++reg)
                        hb[(4 * lg + reg) * 40 + kk] = f2bf(acc[rt][nt][reg]);
                }
                short8v af2 = *(const short8v*)((const char*)hb + lc * 80 + 16 * lg);
                #pragma unroll
                for (int nt2 = 0; nt2 < 4; ++nt2)
                    acc2[rt][nt2] = __builtin_amdgcn_mfma_f32_16x16x32_bf16(af2, bf2[nt2], acc2[rt][nt2], 0, 0, 0);
            }
        }

        // ---- + b2, norms + cosine (in-lane text rt <-> image rt+2) ----
        #pragma unroll
        for (int nt2 = 0; nt2 < 4; ++nt2) {
            float bv = b2[hd * 64 + 16 * nt2 + lc];
            #pragma unroll
            for (int rt = 0; rt < 4; ++rt)
                #pragma unroll
                for (int reg = 0; reg < 4; ++reg) acc2[rt][nt2][reg] += bv;
        }
        #pragma unroll
        for (int rt = 0; rt < 2; ++rt)
            #pragma unroll
            for (int reg = 0; reg < 4; ++reg) {
                float nt_ = 0.f, ni_ = 0.f, pr = 0.f;
                #pragma unroll
                for (int nt2 = 0; nt2 < 4; ++nt2) {
                    float a = acc2[rt][nt2][reg];
                    float b = acc2[rt + 2][nt2][reg];
                    nt_ += a * a; ni_ += b * b; pr += a * b;
                }
                #pragma unroll
                for (int off = 1; off < 16; off <<= 1) {
                    nt_ += __shfl_xor(nt_, off, 64);
                    ni_ += __shfl_xor(ni_, off, 64);
                    pr  += __shfl_xor(pr,  off, 64);
                }
                if (lc == 0) {
                    int bl = 16 * rt + 4 * lg + reg;   // 0..31
                    float denom = fmaxf(sqrtf(nt_), 1e-12f) * fmaxf(sqrtf(ni_), 1e-12f);
                    float cosv = pr / denom;
                    out_pa[(row0 + bl) * 8 + hd] = cosv;
                    sPa[bl][hd] = cosv;
                }
            }
    }

    // ================= global task: cols [128w, 128w+128) =================
    {
        f32x4 accg[2][8];
        #pragma unroll
        for (int rt = 0; rt < 2; ++rt)
            #pragma unroll
            for (int nt = 0; nt < 8; ++nt) accg[rt][nt] = (f32x4){0.f, 0.f, 0.f, 0.f};

        const char* gb = gWb + (8 * w) * 1024 + lane * 16;
        short8v bfA[8], bfB[8];
        #pragma unroll
        for (int nt = 0; nt < 8; ++nt) bfA[nt] = *(const short8v*)(gb + nt * 1024);

        #pragma unroll
        for (int kk = 0; kk < 32; ++kk) {        // kk<16: text x gW1_top, else image x gW1_bot
            short8v* cur = (kk & 1) ? bfB : bfA;
            short8v* nxt = (kk & 1) ? bfA : bfB;
            if (kk + 1 < 32) {
                #pragma unroll
                for (int nt = 0; nt < 8; ++nt)
                    nxt[nt] = *(const short8v*)(gb + (kk + 1) * 32768 + nt * 1024);
            }
            int k0 = kk & 15;
            int rbase = (kk < 16) ? 0 : 32;
            short8v af[2];
            #pragma unroll
            for (int rt = 0; rt < 2; ++rt)
                af[rt] = *(const short8v*)(sXb + (rbase + 16 * rt + lc) * 1024 + ((64 * k0 + 16 * lg) ^ xm));
            #pragma unroll
            for (int nt = 0; nt < 8; ++nt)
                #pragma unroll
                for (int rt = 0; rt < 2; ++rt)
                    accg[rt][nt] = __builtin_amdgcn_mfma_f32_16x16x32_bf16(af[rt], cur[nt], accg[rt][nt], 0, 0, 0);
        }

        // ---- + gb1, LN stats partials ----
        #pragma unroll
        for (int nt = 0; nt < 8; ++nt) {
            float bv = gb1[(8 * w + nt) * 16 + lc];
            #pragma unroll
            for (int rt = 0; rt < 2; ++rt)
                #pragma unroll
                for (int reg = 0; reg < 4; ++reg) accg[rt][nt][reg] += bv;
        }
        #pragma unroll
        for (int rt = 0; rt < 2; ++rt)
            #pragma unroll
            for (int reg = 0; reg < 4; ++reg) {
                float s = 0.f, s2 = 0.f;
                #pragma unroll
                for (int nt = 0; nt < 8; ++nt) { float v = accg[rt][nt][reg]; s += v; s2 += v * v; }
                #pragma unroll
                for (int off = 1; off < 16; off <<= 1) {
                    s += __shfl_xor(s, off, 64);
                    s2 += __shfl_xor(s2, off, 64);
                }
                if (lc == 0) {
                    int r = 16 * rt + 4 * lg + reg;
                    sStat[w][r][0] = s;
                    sStat[w][r][1] = s2;
                }
            }
        __syncthreads();

        float mug[2][4], rsg[2][4];
        #pragma unroll
        for (int rt = 0; rt < 2; ++rt)
            #pragma unroll
            for (int reg = 0; reg < 4; ++reg) {
                int r = 16 * rt + 4 * lg + reg;
                float s = sStat[0][r][0] + sStat[1][r][0] + sStat[2][r][0] + sStat[3][r][0];
                float s2 = sStat[0][r][1] + sStat[1][r][1] + sStat[2][r][1] + sStat[3][r][1];
                float m = s * (1.0f / 512.0f);
                float var = s2 * (1.0f / 512.0f) - m * m;
                mug[rt][reg] = m;
                rsg[rt][reg] = rsqrtf(var + 1e-5f);
            }

        // ---- LN + GELU + dot(gW2) ----
        float dp[2][4];
        #pragma unroll
        for (int rt = 0; rt < 2; ++rt)
            #pragma unroll
            for (int reg = 0; reg < 4; ++reg) dp[rt][reg] = 0.f;
        #pragma unroll
        for (int nt = 0; nt < 8; ++nt) {
            int col = (8 * w + nt) * 16 + lc;
            float gv = glng[col], bv = glnb[col], wv = gW2[col];
            #pragma unroll
            for (int rt = 0; rt < 2; ++rt)
                #pragma unroll
                for (int reg = 0; reg < 4; ++reg) {
                    float v = (accg[rt][nt][reg] - mug[rt][reg]) * rsg[rt][reg] * gv + bv;
                    dp[rt][reg] += gelu_exact(v) * wv;
                }
        }
        #pragma unroll
        for (int rt = 0; rt < 2; ++rt)
            #pragma unroll
            for (int reg = 0; reg < 4; ++reg) {
                float d = dp[rt][reg];
                #pragma unroll
                for (int off = 1; off < 16; off <<= 1) d += __shfl_xor(d, off, 64);
                if (lc == 0) sDot[w][16 * rt + 4 * lg + reg] = d;
            }
        __syncthreads();
    }

    // ================= conflict epilogue =================
    if (tid < 32) {
        int r = tid;
        float z = sDot[0][r] + sDot[1][r] + sDot[2][r] + sDot[3][r] + gb2[0];
        float gs = 1.0f / (1.0f + expf(-z));
        float wv[8], mx = -1e30f;
        #pragma unroll
        for (int i = 0; i < 8; ++i) { wv[i] = aw[i]; mx = fmaxf(mx, wv[i]); }
        float sum = 0.f;
        #pragma unroll
        for (int i = 0; i < 8; ++i) { wv[i] = expf(wv[i] - mx); sum += wv[i]; }
        float inv = 1.0f / sum;
        float wsim = 0.f;
        #pragma unroll
        for (int i = 0; i < 8; ++i) wsim += sPa[r][i] * wv[i] * inv;
        float conf = 1.0f - (0.7f * wsim + 0.3f * gs);
        out_conflict[row0 + r] = fminf(fmaxf(conf, 0.0f), 1.0f);
    }
}

extern "C" void kernel_launch(void* const* d_in, const int* in_sizes, int n_in,
                              void* d_out, int out_size, void* d_ws, size_t ws_size,
                              hipStream_t stream) {
    const float* text  = (const float*)d_in[0];
    const float* image = (const float*)d_in[1];
    const float* W1    = (const float*)d_in[2];
    const float* b1    = (const float*)d_in[3];
    const float* ln1g  = (const float*)d_in[4];
    const float* ln1b  = (const float*)d_in[5];
    const float* W2    = (const float*)d_in[6];
    const float* b2    = (const float*)d_in[7];
    const float* aw    = (const float*)d_in[8];
    const float* gW1   = (const float*)d_in[9];
    const float* gb1   = (const float*)d_in[10];
    const float* glng  = (const float*)d_in[11];
    const float* glnb  = (const float*)d_in[12];
    const float* gW2   = (const float*)d_in[13];
    const float* gb2   = (const float*)d_in[14];

    unsigned short* W1T  = (unsigned short*)d_ws;                          // 1MB
    unsigned short* W2T  = (unsigned short*)((char*)d_ws + 1048576);       // 128KB
    unsigned short* gW1T = (unsigned short*)((char*)d_ws + 1179648);       // 1MB

    float* out = (float*)d_out;
    float* out_pa = out + B_TOTAL;

    convert_weights<<<544, 256, 0, stream>>>(W1, W2, gW1, W1T, W2T, gW1T);
    fused_path<<<2048, 256, 0, stream>>>(text, image, W1T, b1, ln1g, ln1b, W2T, b2,
                                         gW1T, gb1, glng, glnb, gW2, gb2, aw,
                                         out, out_pa);
}